// Round 12
// baseline (413.142 us; speedup 1.0000x reference)
//
#include <hip/hip_runtime.h>
#include <hip/hip_bf16.h>

#define NEGV -1e30f
typedef __attribute__((ext_vector_type(8))) short bf16x8;
typedef __attribute__((ext_vector_type(4))) float f32x4;

__device__ __forceinline__ float rcpf_(float x) { return __builtin_amdgcn_rcpf(x); }
__device__ __forceinline__ float sigmoidf_(float x) { return rcpf_(1.0f + __expf(-x)); }
__device__ __forceinline__ float tanhf_(float x) {
    float ax = fabsf(x);
    float e = __expf(-2.0f * ax);
    float t = (1.0f - e) * rcpf_(1.0f + e);
    return copysignf(t, x);
}
__device__ __forceinline__ float bf2f(unsigned short u) {
    union { float f; unsigned int i; } x; x.i = ((unsigned int)u) << 16; return x.f;
}
__device__ __forceinline__ float bfsel(uint2 v, int rg) {
    unsigned int w = (rg < 2) ? v.x : v.y;
    return bf2f((unsigned short)((rg & 1) ? (w >> 16) : (w & 0xffffu)));
}

// ---------------------------------------------------------------------------
// bf16 MFMA-B swizzles.
// ---------------------------------------------------------------------------
__device__ __forceinline__ void swz_store(const float* __restrict__ src,
    __hip_bfloat16* __restrict__ dst, int idx, int kshift)
{
    int n = idx >> kshift, k = idx & ((1 << kshift) - 1);
    int nt = n >> 4, kt = k >> 5, quad = (k & 31) >> 3, pos = k & 7;
    dst[((size_t)((nt << (kshift - 5)) + kt) * 64 + quad * 16 + (n & 15)) * 8 + pos] =
        (__hip_bfloat16)src[idx];
}

__device__ __forceinline__ void swz_store_g(const float* __restrict__ src,
    __hip_bfloat16* __restrict__ dst, int idx, int kshift)
{
    int n = idx >> kshift, k = idx & ((1 << kshift) - 1);
    int gate = n >> 8, c = n & 255, w = c >> 5, half = (c >> 4) & 1;
    int tileG = w * 6 + gate * 2 + half;
    int kt = k >> 5, quad = (k & 31) >> 3, pos = k & 7;
    dst[((size_t)((tileG << (kshift - 5)) + kt) * 64 + quad * 16 + (n & 15)) * 8 + pos] =
        (__hip_bfloat16)src[idx];
}

// ---------------------------------------------------------------------------
// convert_all v3: weight swizzles + Wk TRANSPOSE swizzle (for G = Qb @ Wk)
// + fused wqb GEMM tail.
// blocks [0,2816): element swizzles; [2816,3072): Wk^T B-frag swizzle
// ((n=d,k=h) = Wk[h][d], coalesced reads / scattered stores);
// [3072,3088): wqb = Wbil^T @ Wq, bf16-swizzled epilogue.
// ---------------------------------------------------------------------------
__global__ __launch_bounds__(256) void convert_all(
    const float* __restrict__ Wih_n, const float* __restrict__ Wih_g,
    const float* __restrict__ Whh_n, const float* __restrict__ Whh_g,
    const float* __restrict__ Wk_,   const float* __restrict__ Wv_,
    const float* __restrict__ Wbil_, const float* __restrict__ Wq_,
    __hip_bfloat16* Wih_n_sw, __hip_bfloat16* Wih_g_sw,
    __hip_bfloat16* Whh_n_sw, __hip_bfloat16* Whh_g_sw,
    __hip_bfloat16* Wk_sw, __hip_bfloat16* Wv_sw, __hip_bfloat16* wqb_sw,
    __hip_bfloat16* Wk_t_sw)
{
    __shared__ __align__(16) float As[32 * 68];
    __shared__ __align__(16) float Bs[32 * 68];
    if (blockIdx.x < 2816) {
        int g = blockIdx.x * 256 + threadIdx.x;   // < 720896
        if (g < 98304)        swz_store_g(Wih_n, Wih_n_sw, g, 7);
        else if (g < 196608)  swz_store_g(Wih_g, Wih_g_sw, g - 98304, 7);
        else if (g < 393216)  swz_store_g(Whh_n, Whh_n_sw, g - 196608, 8);
        else if (g < 589824)  swz_store_g(Whh_g, Whh_g_sw, g - 393216, 8);
        else if (g < 655360)  swz_store(Wk_,   Wk_sw,   g - 589824, 8);
        else                  swz_store(Wv_,   Wv_sw,   g - 655360, 8);
        return;
    }
    if (blockIdx.x < 3072) {
        // Wk^T: frag element (n=d, k=h) = Wk[h][d]
        int g = (blockIdx.x - 2816) * 256 + threadIdx.x;  // [0, 65536)
        int k = g >> 8, n = g & 255;                      // k=h, n=d
        float v = Wk_[(size_t)k * 256 + n];               // coalesced read
        int nt = n >> 4, kt = k >> 5, quad = (k & 31) >> 3, pos = k & 7;
        Wk_t_sw[((size_t)(nt * 8 + kt) * 64 + quad * 16 + (n & 15)) * 8 + pos] =
            (__hip_bfloat16)v;
        return;
    }
    const int bx = blockIdx.x - 3072;
    const int tid = threadIdx.x, tx = tid & 15, ty = tid >> 4;
    const int rb = (bx >> 2) * 64, cb = (bx & 3) * 64;
    float acc[4][4] = {};
    for (int k0 = 0; k0 < 256; k0 += 32) {
        __syncthreads();
        for (int f = tid; f < 2048; f += 256) {
            int kk = f >> 6, r = f & 63;
            As[kk * 68 + r] = Wbil_[(size_t)(k0 + kk) * 256 + rb + r];
        }
        for (int f = tid; f < 2048; f += 256) {
            int kk = f >> 6, c = f & 63;
            Bs[kk * 68 + c] = Wq_[(size_t)(k0 + kk) * 256 + cb + c];
        }
        __syncthreads();
#pragma unroll
        for (int kk = 0; kk < 32; ++kk) {
            float4 a4 = *(const float4*)(As + kk * 68 + ty * 4);
            float4 b4 = *(const float4*)(Bs + kk * 68 + tx * 4);
            float av[4] = {a4.x, a4.y, a4.z, a4.w};
            float bv[4] = {b4.x, b4.y, b4.z, b4.w};
#pragma unroll
            for (int i = 0; i < 4; ++i)
#pragma unroll
                for (int j = 0; j < 4; ++j) acc[i][j] += av[i] * bv[j];
        }
    }
#pragma unroll
    for (int i = 0; i < 4; ++i)
#pragma unroll
        for (int j = 0; j < 4; ++j) {
            int n = rb + ty * 4 + i, k = cb + tx * 4 + j;
            int nt = n >> 4, kt = k >> 5, quad = (k & 31) >> 3, pos = k & 7;
            wqb_sw[((size_t)(nt * 8 + kt) * 64 + quad * 16 + (n & 15)) * 8 + pos] =
                (__hip_bfloat16)acc[i][j];
        }
}

// ---------------------------------------------------------------------------
// gi_gemm v2 (validated round 11 — unchanged).
// ---------------------------------------------------------------------------
__global__ __launch_bounds__(512) void gi_gemm(
    const float* __restrict__ node_input, const float* __restrict__ neighbors_input,
    const __hip_bfloat16* __restrict__ Wih_n_sw, const __hip_bfloat16* __restrict__ Wih_g_sw,
    const float* __restrict__ bih_node, const float* __restrict__ bhh_node,
    const float* __restrict__ bih_ngh,  const float* __restrict__ bhh_ngh,
    __hip_bfloat16* __restrict__ gi)
{
    __shared__ __align__(16) __hip_bfloat16 xs[64 * 136];
    const int tid = threadIdx.x, wave = tid >> 6, lane = tid & 63;
    const int quad = lane >> 4, lr = lane & 15;
    const int sblk = blockIdx.x >> 4, tc = blockIdx.x & 15;
    const bool isnode = (sblk < 4);
    const float* __restrict__ xb = isnode
        ? (node_input + (size_t)sblk * 16 * 64 * 128)
        : (neighbors_input + ((size_t)sblk * 16 - 64) * 64 * 128);
    const __hip_bfloat16* __restrict__ Wsw = isnode ? Wih_n_sw : Wih_g_sw;
    const float* __restrict__ bi = isnode ? bih_node : bih_ngh;
    const float* __restrict__ bh = isnode ? bhh_node : bhh_ngh;

    bf16x8 wfr[24];
#pragma unroll
    for (int nt = 0; nt < 6; ++nt)
#pragma unroll
        for (int kt = 0; kt < 4; ++kt)
            wfr[nt * 4 + kt] = *(const bf16x8*)(const void*)(
                Wsw + ((size_t)((wave * 6 + nt) * 4 + kt) * 64 + lane) * 8);

    float bias6[6];
#pragma unroll
    for (int tl = 0; tl < 6; ++tl) {
        int gate = tl >> 1;
        int col = gate * 256 + wave * 32 + (tl & 1) * 16 + lr;
        bias6[tl] = bi[col] + (gate < 2 ? bh[col] : 0.0f);
    }

    // stage 16 rows x 4 t-steps: vrow = r*4 + tt, 128 cols each
    {
        const int vr = tid >> 3, c0 = (tid & 7) * 16;
        const int r = vr >> 2, tt = vr & 3;
        const float* src = xb + ((size_t)r * 64 + tc * 4 + tt) * 128 + c0;
        float4 v0 = *(const float4*)(src);
        float4 v1 = *(const float4*)(src + 4);
        float4 v2 = *(const float4*)(src + 8);
        float4 v3 = *(const float4*)(src + 12);
        float vv[16] = {v0.x, v0.y, v0.z, v0.w, v1.x, v1.y, v1.z, v1.w,
                        v2.x, v2.y, v2.z, v2.w, v3.x, v3.y, v3.z, v3.w};
        __hip_bfloat16* d = xs + vr * 136 + c0;
#pragma unroll
        for (int j = 0; j < 16; ++j) d[j] = (__hip_bfloat16)vv[j];
    }
    __syncthreads();

    __hip_bfloat16* __restrict__ gout =
        gi + (size_t)((sblk * 8 + wave) * 6) * 16384 + (size_t)lane * 4;

#pragma unroll
    for (int tt = 0; tt < 4; ++tt) {
        int t = tc * 4 + tt;
        bf16x8 afr[4];
#pragma unroll
        for (int kt = 0; kt < 4; ++kt)
            afr[kt] = *(const bf16x8*)(const void*)(xs + (lr * 4 + tt) * 136 + kt * 32 + quad * 8);

#pragma unroll
        for (int tl = 0; tl < 6; ++tl) {
            f32x4 acc = {0.f, 0.f, 0.f, 0.f};
#pragma unroll
            for (int kt = 0; kt < 4; ++kt)
                acc = __builtin_amdgcn_mfma_f32_16x16x32_bf16(afr[kt], wfr[tl * 4 + kt], acc, 0, 0, 0);
            union { __hip_bfloat16 p[4]; uint2 u; } pu;
#pragma unroll
            for (int rg = 0; rg < 4; ++rg) pu.p[rg] = (__hip_bfloat16)(acc[rg] + bias6[tl]);
            *(uint2*)(void*)(gout + (size_t)tl * 16384 + (size_t)t * 256) = pu.u;
        }
    }
}

// ---------------------------------------------------------------------------
// scan_kernel (measured-best round-4/6 config — control, unchanged).
// ---------------------------------------------------------------------------
__global__ __launch_bounds__(512, 2) void scan_kernel(
    const __hip_bfloat16* __restrict__ gi,
    const __hip_bfloat16* __restrict__ Whh_n_sw,
    const __hip_bfloat16* __restrict__ Whh_g_sw,
    const float* __restrict__ bhh_node, const float* __restrict__ bhh_ngh,
    const float* __restrict__ node_hidden, const float* __restrict__ neighbors_hidden,
    __hip_bfloat16* __restrict__ node_out, __hip_bfloat16* __restrict__ ngh_out,
    float* __restrict__ out_node_hT, float* __restrict__ out_ngh_hT)
{
    __shared__ __align__(16) __hip_bfloat16 wlds[96 * 64 * 8];
    __shared__ __align__(16) __hip_bfloat16 hfr[2 * 4096];
    const int tid = threadIdx.x;
    const int wave = tid >> 6, lane = tid & 63;
    const int quad = lane >> 4, lr = lane & 15;
    const int row0 = blockIdx.x * 16;
    const bool isnode = (row0 < 64);
    const __hip_bfloat16* __restrict__ Wsw = isnode ? Whh_n_sw : Whh_g_sw;
    const float* __restrict__ bhh = isnode ? bhh_node : bhh_ngh;

    bf16x8 wreg[36];
#pragma unroll
    for (int nt = 0; nt < 6; ++nt)
#pragma unroll
        for (int kt = 0; kt < 6; ++kt)
            wreg[nt * 6 + kt] = *(const bf16x8*)(const void*)(
                Wsw + ((size_t)((wave * 6 + nt) * 8 + kt) * 64 + lane) * 8);

    for (int f = tid; f < 6144; f += 512) {
        int chunk = f >> 6, l = f & 63;
        int tileG = chunk >> 1, s = chunk & 1;
        *(uint4*)(void*)(wlds + ((size_t)chunk * 64 + l) * 8) =
            *(const uint4*)(const void*)(Wsw + ((size_t)(tileG * 8 + 6 + s) * 64 + l) * 8);
    }

    const __hip_bfloat16* __restrict__ gbase =
        gi + (size_t)((blockIdx.x * 8 + wave) * 6) * 16384 + (size_t)lane * 4;

    const float bhn0 = bhh[512 + wave * 32 + lr];
    const float bhn1 = bhh[512 + wave * 32 + 16 + lr];

    const int hwoff = (wave * 64 + (lr >> 3) * 16 + quad * 4) * 8 + (lr & 7);
    float hreg[8];
    {
        const float* hsrc = isnode ? (node_hidden + (size_t)row0 * 256)
                                   : (neighbors_hidden + (size_t)(row0 - 64) * 256);
#pragma unroll
        for (int half = 0; half < 2; ++half)
#pragma unroll
            for (int rg = 0; rg < 4; ++rg) {
                float v = hsrc[(size_t)(quad * 4 + rg) * 256 + wave * 32 + half * 16 + lr];
                hreg[half * 4 + rg] = v;
                hfr[hwoff + half * 256 + rg * 8] = (__hip_bfloat16)v;
            }
    }

    __hip_bfloat16* optr;
    {
        int orow = tid & 15;
        int ocol = (tid >> 6) * 32 + ((tid >> 4) & 3) * 8;
        optr = isnode ? (node_out + ((size_t)(row0 + orow) * 64) * 256 + ocol)
                      : (ngh_out + ((size_t)(row0 - 64 + orow) * 64) * 256 + ocol);
    }

    uint2 gv[6];
#pragma unroll
    for (int tl = 0; tl < 6; ++tl)
        gv[tl] = *(const uint2*)(const void*)(gbase + (size_t)tl * 16384);

    __syncthreads();

#pragma unroll 1
    for (int t = 0; t < 64; ++t) {
        const __hip_bfloat16* hr = hfr + (t & 1) * 4096;

        const int tp = (t < 63) ? (t + 1) : 63;
        uint2 gvn[6];
#pragma unroll
        for (int tl = 0; tl < 6; ++tl)
            gvn[tl] = *(const uint2*)(const void*)(gbase + (size_t)tl * 16384 + tp * 256);

        if (t) {
            uint4 ov = *(const uint4*)(const void*)(hr + tid * 8);
            *(uint4*)(void*)optr = ov;
            optr += 256;
        }

        f32x4 acc[6] = {{0.f,0.f,0.f,0.f},{0.f,0.f,0.f,0.f},{0.f,0.f,0.f,0.f},
                        {0.f,0.f,0.f,0.f},{0.f,0.f,0.f,0.f},{0.f,0.f,0.f,0.f}};
        {
#pragma unroll
            for (int kt = 0; kt < 3; ++kt) {
                bf16x8 av = *(const bf16x8*)(const void*)(hr + (kt * 64 + lane) * 8);
#pragma unroll
                for (int tl = 0; tl < 6; ++tl)
                    acc[tl] = __builtin_amdgcn_mfma_f32_16x16x32_bf16(av, wreg[tl * 6 + kt], acc[tl], 0, 0, 0);
            }
        }
        {
#pragma unroll
            for (int kt = 3; kt < 6; ++kt) {
                bf16x8 av = *(const bf16x8*)(const void*)(hr + (kt * 64 + lane) * 8);
#pragma unroll
                for (int tl = 0; tl < 6; ++tl)
                    acc[tl] = __builtin_amdgcn_mfma_f32_16x16x32_bf16(av, wreg[tl * 6 + kt], acc[tl], 0, 0, 0);
            }
        }
        {
#pragma unroll
            for (int s = 0; s < 2; ++s) {
                bf16x8 av = *(const bf16x8*)(const void*)(hr + ((6 + s) * 64 + lane) * 8);
#pragma unroll
                for (int tl = 0; tl < 6; ++tl) {
                    bf16x8 bfr = *(const bf16x8*)(const void*)(
                        wlds + ((size_t)((wave * 6 + tl) * 2 + s) * 64 + lane) * 8);
                    acc[tl] = __builtin_amdgcn_mfma_f32_16x16x32_bf16(av, bfr, acc[tl], 0, 0, 0);
                }
            }
        }

        __hip_bfloat16* hw = hfr + ((t + 1) & 1) * 4096 + hwoff;
#pragma unroll
        for (int half = 0; half < 2; ++half) {
            const float bhn = half ? bhn1 : bhn0;
#pragma unroll
            for (int rg = 0; rg < 4; ++rg) {
                float ghr = acc[half][rg];
                float ghz = acc[2 + half][rg];
                float ghn = acc[4 + half][rg] + bhn;
                float gir = bfsel(gv[half], rg);
                float giz = bfsel(gv[2 + half], rg);
                float gin = bfsel(gv[4 + half], rg);
                float r = sigmoidf_(gir + ghr);
                float z = sigmoidf_(giz + ghz);
                float n = tanhf_(gin + r * ghn);
                float hn = (1.0f - z) * n + z * hreg[half * 4 + rg];
                hreg[half * 4 + rg] = hn;
                hw[half * 256 + rg * 8] = (__hip_bfloat16)hn;
            }
        }
#pragma unroll
        for (int tl = 0; tl < 6; ++tl) gv[tl] = gvn[tl];

        asm volatile("s_waitcnt lgkmcnt(0)" ::: "memory");
        __builtin_amdgcn_s_barrier();
        __builtin_amdgcn_sched_barrier(0);
    }

    {
        uint4 ov = *(const uint4*)(const void*)(hfr + tid * 8);
        *(uint4*)(void*)optr = ov;
    }
    {
        float* hdst = isnode ? (out_node_hT + (size_t)row0 * 256)
                             : (out_ngh_hT + (size_t)(row0 - 64) * 256);
#pragma unroll
        for (int half = 0; half < 2; ++half)
#pragma unroll
            for (int rg = 0; rg < 4; ++rg)
                hdst[(size_t)(quad * 4 + rg) * 256 + wave * 32 + half * 16 + lr] = hreg[half * 4 + rg];
    }
}

// ---------------------------------------------------------------------------
// q_gemm v2: G = (node_out @ wqb) @ Wk — two chained 64x256x256 GEMMs per
// block. Qb intermediate is bf16-rounded (replaces the old K rounding) and
// round-trips through As. 64 blocks. attn consumes G in place of Qb.
// ---------------------------------------------------------------------------
__global__ __launch_bounds__(256) void q_gemm(
    const __hip_bfloat16* __restrict__ A0,
    const __hip_bfloat16* __restrict__ wqb_sw,
    const __hip_bfloat16* __restrict__ Wk_t_sw,
    __hip_bfloat16* __restrict__ G)
{
    __shared__ __align__(16) __hip_bfloat16 As[64 * 264];
    const int tid = threadIdx.x, wave = tid >> 6, lane = tid & 63;
    const int quad = lane >> 4, lr = lane & 15;
    const int rb = blockIdx.x * 64;
    const __hip_bfloat16* A = A0 + (size_t)rb * 256;

    for (int f = tid; f < 2048; f += 256) {
        int row = f >> 5, cc = (f & 31) * 8;
        *(uint4*)(void*)(As + row * 264 + cc) =
            *(const uint4*)(const void*)(A + (size_t)row * 256 + cc);
    }
    __syncthreads();

    bf16x8 afr[8];
#pragma unroll
    for (int kt = 0; kt < 8; ++kt)
        afr[kt] = *(const bf16x8*)(const void*)(As + (wave * 16 + lr) * 264 + kt * 32 + quad * 8);
    __syncthreads();   // all afr extracted -> As may be overwritten with Qb

    const int s0 = wave * 16 + quad * 4;
    // GEMM1: Qb = A @ wqb^T -> As rows (bf16)
    for (int ntg = 0; ntg < 16; ++ntg) {
        f32x4 acc = {0.f, 0.f, 0.f, 0.f};
#pragma unroll
        for (int kt = 0; kt < 8; ++kt) {
            bf16x8 bfr = *(const bf16x8*)(const void*)(wqb_sw + ((size_t)(ntg * 8 + kt) * 64 + lane) * 8);
            acc = __builtin_amdgcn_mfma_f32_16x16x32_bf16(afr[kt], bfr, acc, 0, 0, 0);
        }
        int col = ntg * 16 + lr;
#pragma unroll
        for (int rg = 0; rg < 4; ++rg)
            As[(s0 + rg) * 264 + col] = (__hip_bfloat16)acc[rg];
    }
    __syncthreads();

    // GEMM2: G = Qb @ Wk (Wk^T frags)
    bf16x8 qfr[8];
#pragma unroll
    for (int kt = 0; kt < 8; ++kt)
        qfr[kt] = *(const bf16x8*)(const void*)(As + (wave * 16 + lr) * 264 + kt * 32 + quad * 8);
    for (int ntg = 0; ntg < 16; ++ntg) {
        f32x4 acc = {0.f, 0.f, 0.f, 0.f};
#pragma unroll
        for (int kt = 0; kt < 8; ++kt) {
            bf16x8 bfr = *(const bf16x8*)(const void*)(Wk_t_sw + ((size_t)(ntg * 8 + kt) * 64 + lane) * 8);
            acc = __builtin_amdgcn_mfma_f32_16x16x32_bf16(qfr[kt], bfr, acc, 0, 0, 0);
        }
        int col = ntg * 16 + lr;
#pragma unroll
        for (int rg = 0; rg < 4; ++rg)
            G[(size_t)(rb + s0 + rg) * 256 + col] = (__hip_bfloat16)acc[rg];
    }
}

// ---------------------------------------------------------------------------
// attn_fused v2: S = G @ A_m^T — the per-block K-GEMM (128 MFMA + K LDS
// round-trip + 1 barrier) is GONE; the S-phase reads the staged A-tile
// directly as B-frags (same index expression as the old K read).
// ---------------------------------------------------------------------------
__global__ __launch_bounds__(256) void attn_fused(
    const __hip_bfloat16* __restrict__ node_out_b,
    const __hip_bfloat16* __restrict__ ngh_out_b,
    const __hip_bfloat16* __restrict__ Wv_sw,
    const __hip_bfloat16* __restrict__ G, const float* __restrict__ bbil,
    const float* __restrict__ Wprj, const float* __restrict__ bprj,
    float* __restrict__ A_out, float* __restrict__ out)
{
    __shared__ __align__(16) __hip_bfloat16 KA[64 * 264];   // A-tile -> Vfrag
    __shared__ __align__(16) float Sbuf[64 * 68];
    __shared__ __align__(16) __hip_bfloat16 Pb[64 * 72];
    __shared__ float rowmax[64], rowrcp[64];
    __shared__ float red[64 * 16];
    const int tid = threadIdx.x;
    const int wave = tid >> 6, lane = tid & 63;
    const int quad = lane >> 4, lr = lane & 15;
    const int bm = blockIdx.x, b = bm / 17, m = bm % 17;
    const __hip_bfloat16* __restrict__ A = (m == 0)
        ? (node_out_b + (size_t)b * 64 * 256)
        : (ngh_out_b + ((size_t)(b * 16 + m - 1) * 64) * 256);

    // phase 0: stage A-tile
    for (int f = tid; f < 2048; f += 256) {
        int row = f >> 5, cc = (f & 31) * 8;
        *(uint4*)(void*)(KA + row * 264 + cc) =
            *(const uint4*)(const void*)(A + (size_t)row * 256 + cc);
    }
    __syncthreads();

    // phase 1: afr (for V) + gfr (G frags, L2-hot) + S = G @ A^T from KA
    bf16x8 afr[8];
#pragma unroll
    for (int kt = 0; kt < 8; ++kt)
        afr[kt] = *(const bf16x8*)(const void*)(KA + (wave * 16 + lr) * 264 + kt * 32 + quad * 8);
    const __hip_bfloat16* Grow = G + (size_t)b * 64 * 256;
    bf16x8 gfr[8];
#pragma unroll
    for (int kt = 0; kt < 8; ++kt)
        gfr[kt] = *(const bf16x8*)(const void*)(Grow + (size_t)(wave * 16 + lr) * 256 + kt * 32 + quad * 8);

    f32x4 sacc[4] = {{0.f,0.f,0.f,0.f},{0.f,0.f,0.f,0.f},{0.f,0.f,0.f,0.f},{0.f,0.f,0.f,0.f}};
#pragma unroll
    for (int kt = 0; kt < 8; ++kt) {
#pragma unroll
        for (int c = 0; c < 4; ++c) {
            bf16x8 bfr = *(const bf16x8*)(const void*)(KA + (c * 16 + lr) * 264 + kt * 32 + quad * 8);
            sacc[c] = __builtin_amdgcn_mfma_f32_16x16x32_bf16(gfr[kt], bfr, sacc[c], 0, 0, 0);
        }
    }
#pragma unroll
    for (int c = 0; c < 4; ++c)
#pragma unroll
        for (int rg = 0; rg < 4; ++rg) {
            int t_ = wave * 16 + quad * 4 + rg, s_ = c * 16 + lr;
            Sbuf[t_ * 68 + s_] = (s_ <= t_) ? (sacc[c][rg] + bbil[s_]) : NEGV;
        }
    __syncthreads();   // S-MFMA + afr reads of KA done -> V may overwrite

    // phase 2: V = A @ Wv^T -> KA as PV B-frags; softmax on tid<64
    {
        const int kt2 = wave >> 1;
        const int lp = ((wave & 1) * 2 + (quad >> 1)) * 16 + lr;
        const int j0 = (quad & 1) * 4;
        for (int ntg = 0; ntg < 16; ++ntg) {
            f32x4 acc = {0.f, 0.f, 0.f, 0.f};
#pragma unroll
            for (int kt = 0; kt < 8; ++kt) {
                bf16x8 bfr = *(const bf16x8*)(const void*)(Wv_sw + ((size_t)(ntg * 8 + kt) * 64 + lane) * 8);
                acc = __builtin_amdgcn_mfma_f32_16x16x32_bf16(afr[kt], bfr, acc, 0, 0, 0);
            }
            __hip_bfloat16 t4[4];
#pragma unroll
            for (int rg = 0; rg < 4; ++rg) t4[rg] = (__hip_bfloat16)acc[rg];
            *(uint2*)(void*)(KA + (size_t)(((ntg * 2 + kt2) * 64 + lp) * 8 + j0)) =
                *(const uint2*)(const void*)t4;
        }
    }
    if (tid < 64) {
        float mx = -3.0e38f;
        for (int s = 0; s < 64; ++s) mx = fmaxf(mx, Sbuf[tid * 68 + s]);
        float sum = 0.0f;
        for (int s = 0; s < 64; ++s) sum += __expf(Sbuf[tid * 68 + s] - mx);
        rowmax[tid] = mx;
        rowrcp[tid] = 1.0f / sum;
    }
    __syncthreads();

    // phase 3: P = softmax(S) -> A_out + Pb
    for (int idx = tid; idx < 4096; idx += 256) {
        int t_ = idx >> 6, s_ = idx & 63;
        float e = __expf(Sbuf[t_ * 68 + s_] - rowmax[t_]) * rowrcp[t_];
        A_out[(size_t)bm * 4096 + idx] = e;
        Pb[t_ * 72 + s_] = (__hip_bfloat16)e;
    }
    __syncthreads();

    // phase 4: ctx = P V, proj, reduce
    bf16x8 pfr[2];
#pragma unroll
    for (int k2 = 0; k2 < 2; ++k2)
        pfr[k2] = *(const bf16x8*)(const void*)(Pb + (wave * 16 + lr) * 72 + k2 * 32 + quad * 8);
    float part[4] = {0.f, 0.f, 0.f, 0.f};
#pragma unroll
    for (int nt = 0; nt < 16; ++nt) {
        f32x4 cacc = {0.f, 0.f, 0.f, 0.f};
#pragma unroll
        for (int k2 = 0; k2 < 2; ++k2) {
            bf16x8 bfr = *(const bf16x8*)(const void*)(KA + (size_t)((nt * 2 + k2) * 64 + lane) * 8);
            cacc = __builtin_amdgcn_mfma_f32_16x16x32_bf16(pfr[k2], bfr, cacc, 0, 0, 0);
        }
        float wp = Wprj[nt * 16 + lr];
#pragma unroll
        for (int rg = 0; rg < 4; ++rg) part[rg] += cacc[rg] * wp;
    }
#pragma unroll
    for (int rg = 0; rg < 4; ++rg) red[(wave * 16 + quad * 4 + rg) * 16 + lr] = part[rg];
    __syncthreads();
    if (tid < 64) {
        float s = 0.0f;
#pragma unroll
        for (int q = 0; q < 16; ++q) s += red[tid * 16 + q];
        if (m == 0) s += 17.0f * bprj[0];
        atomicAdd(out + b * 64 + tid, s);
    }
}

// ---------------------------------------------------------------------------
extern "C" void kernel_launch(void* const* d_in, const int* in_sizes, int n_in,
                              void* d_out, int out_size, void* d_ws, size_t ws_size,
                              hipStream_t stream)
{
    const float* node_input       = (const float*)d_in[0];
    const float* node_hidden      = (const float*)d_in[1];
    const float* neighbors_input  = (const float*)d_in[2];
    const float* neighbors_hidden = (const float*)d_in[3];
    const float* Wih_node = (const float*)d_in[5];
    const float* Whh_node = (const float*)d_in[6];
    const float* bih_node = (const float*)d_in[7];
    const float* bhh_node = (const float*)d_in[8];
    const float* Wih_ngh  = (const float*)d_in[9];
    const float* Whh_ngh  = (const float*)d_in[10];
    const float* bih_ngh  = (const float*)d_in[11];
    const float* bhh_ngh  = (const float*)d_in[12];
    const float* Wq   = (const float*)d_in[13];
    const float* Wk   = (const float*)d_in[14];
    const float* Wv   = (const float*)d_in[15];
    const float* Wbil = (const float*)d_in[16];
    const float* bbil = (const float*)d_in[17];
    const float* Wprj = (const float*)d_in[18];
    const float* bprj = (const float*)d_in[19];

    float* out         = (float*)d_out;          // (B,T)     4096
    float* out_node_hT = out + 4096;             // (1,B,H)   16384
    float* out_ngh_hT  = out + 20480;            // (1,B*N,H) 262144
    float* out_A       = out + 282624;           // (B,17,T,T)

    // ---- workspace layout (bytes) ----
    char* w = (char*)d_ws;
    __hip_bfloat16* Wk_t_sw  = (__hip_bfloat16*)(w);             // 131072 (old wqb_f slot)
    __hip_bfloat16* Wih_n_sw = (__hip_bfloat16*)(w + 262144);    // 196608
    __hip_bfloat16* Wih_g_sw = (__hip_bfloat16*)(w + 458752);    // 196608
    __hip_bfloat16* Whh_n_sw = (__hip_bfloat16*)(w + 655360);    // 393216
    __hip_bfloat16* Whh_g_sw = (__hip_bfloat16*)(w + 1048576);   // 393216
    __hip_bfloat16* Wk_sw    = (__hip_bfloat16*)(w + 1441792);   // 131072 (unused, kept)
    __hip_bfloat16* Wv_sw    = (__hip_bfloat16*)(w + 1572864);   // 131072
    __hip_bfloat16* wqb_sw   = (__hip_bfloat16*)(w + 1703936);   // 131072
    __hip_bfloat16* node_out_b = (__hip_bfloat16*)(w + 1835008); // 2097152
    __hip_bfloat16* ngh_out_b  = (__hip_bfloat16*)(w + 3932160); // 33554432
    __hip_bfloat16* g_b        = (__hip_bfloat16*)(w + 37486592);// 2097152
    __hip_bfloat16* gi         = (__hip_bfloat16*)(w + 39583744);// 106954752
    // end: 146538496 B

    hipMemsetAsync(d_out, 0, 4096 * sizeof(float), stream);

    convert_all<<<3088, 256, 0, stream>>>(
        Wih_node, Wih_ngh, Whh_node, Whh_ngh, Wk, Wv, Wbil, Wq,
        Wih_n_sw, Wih_g_sw, Whh_n_sw, Whh_g_sw, Wk_sw, Wv_sw, wqb_sw, Wk_t_sw);

    gi_gemm<<<1088, 512, 0, stream>>>(
        node_input, neighbors_input, Wih_n_sw, Wih_g_sw,
        bih_node, bhh_node, bih_ngh, bhh_ngh, gi);

    scan_kernel<<<68, 512, 0, stream>>>(gi, Whh_n_sw, Whh_g_sw,
        bhh_node, bhh_ngh, node_hidden, neighbors_hidden,
        node_out_b, ngh_out_b, out_node_hT, out_ngh_hT);

    q_gemm<<<64, 256, 0, stream>>>(node_out_b, wqb_sw, Wk_t_sw, g_b);

    attn_fused<<<1088, 256, 0, stream>>>(
        node_out_b, ngh_out_b, Wv_sw, g_b, bbil, Wprj, bprj,
        out_A, out);
}

// Round 13
// 390.905 us; speedup vs baseline: 1.0569x; 1.0569x over previous
//
#include <hip/hip_runtime.h>
#include <hip/hip_bf16.h>

#define NEGV -1e30f
typedef __attribute__((ext_vector_type(8))) short bf16x8;
typedef __attribute__((ext_vector_type(4))) float f32x4;

__device__ __forceinline__ float rcpf_(float x) { return __builtin_amdgcn_rcpf(x); }
__device__ __forceinline__ float sigmoidf_(float x) { return rcpf_(1.0f + __expf(-x)); }
__device__ __forceinline__ float tanhf_(float x) {
    float ax = fabsf(x);
    float e = __expf(-2.0f * ax);
    float t = (1.0f - e) * rcpf_(1.0f + e);
    return copysignf(t, x);
}
__device__ __forceinline__ float bf2f(unsigned short u) {
    union { float f; unsigned int i; } x; x.i = ((unsigned int)u) << 16; return x.f;
}
__device__ __forceinline__ float bfsel(uint2 v, int rg) {
    unsigned int w = (rg < 2) ? v.x : v.y;
    return bf2f((unsigned short)((rg & 1) ? (w >> 16) : (w & 0xffffu)));
}

// ---------------------------------------------------------------------------
// bf16 MFMA-B swizzles.
// ---------------------------------------------------------------------------
__device__ __forceinline__ void swz_store(const float* __restrict__ src,
    __hip_bfloat16* __restrict__ dst, int idx, int kshift)
{
    int n = idx >> kshift, k = idx & ((1 << kshift) - 1);
    int nt = n >> 4, kt = k >> 5, quad = (k & 31) >> 3, pos = k & 7;
    dst[((size_t)((nt << (kshift - 5)) + kt) * 64 + quad * 16 + (n & 15)) * 8 + pos] =
        (__hip_bfloat16)src[idx];
}

__device__ __forceinline__ void swz_store_g(const float* __restrict__ src,
    __hip_bfloat16* __restrict__ dst, int idx, int kshift)
{
    int n = idx >> kshift, k = idx & ((1 << kshift) - 1);
    int gate = n >> 8, c = n & 255, w = c >> 5, half = (c >> 4) & 1;
    int tileG = w * 6 + gate * 2 + half;
    int kt = k >> 5, quad = (k & 31) >> 3, pos = k & 7;
    dst[((size_t)((tileG << (kshift - 5)) + kt) * 64 + quad * 16 + (n & 15)) * 8 + pos] =
        (__hip_bfloat16)src[idx];
}

// ---------------------------------------------------------------------------
// convert_all v2: swizzles + fused wqb GEMM tail (validated round 6).
// ---------------------------------------------------------------------------
__global__ __launch_bounds__(256) void convert_all(
    const float* __restrict__ Wih_n, const float* __restrict__ Wih_g,
    const float* __restrict__ Whh_n, const float* __restrict__ Whh_g,
    const float* __restrict__ Wk_,   const float* __restrict__ Wv_,
    const float* __restrict__ Wbil_, const float* __restrict__ Wq_,
    __hip_bfloat16* Wih_n_sw, __hip_bfloat16* Wih_g_sw,
    __hip_bfloat16* Whh_n_sw, __hip_bfloat16* Whh_g_sw,
    __hip_bfloat16* Wk_sw, __hip_bfloat16* Wv_sw, __hip_bfloat16* wqb_sw)
{
    __shared__ __align__(16) float As[32 * 68];
    __shared__ __align__(16) float Bs[32 * 68];
    if (blockIdx.x < 2816) {
        int g = blockIdx.x * 256 + threadIdx.x;   // < 720896
        if (g < 98304)        swz_store_g(Wih_n, Wih_n_sw, g, 7);
        else if (g < 196608)  swz_store_g(Wih_g, Wih_g_sw, g - 98304, 7);
        else if (g < 393216)  swz_store_g(Whh_n, Whh_n_sw, g - 196608, 8);
        else if (g < 589824)  swz_store_g(Whh_g, Whh_g_sw, g - 393216, 8);
        else if (g < 655360)  swz_store(Wk_,   Wk_sw,   g - 589824, 8);
        else                  swz_store(Wv_,   Wv_sw,   g - 655360, 8);
        return;
    }
    const int bx = blockIdx.x - 2816;
    const int tid = threadIdx.x, tx = tid & 15, ty = tid >> 4;
    const int rb = (bx >> 2) * 64, cb = (bx & 3) * 64;
    float acc[4][4] = {};
    for (int k0 = 0; k0 < 256; k0 += 32) {
        __syncthreads();
        for (int f = tid; f < 2048; f += 256) {
            int kk = f >> 6, r = f & 63;
            As[kk * 68 + r] = Wbil_[(size_t)(k0 + kk) * 256 + rb + r];
        }
        for (int f = tid; f < 2048; f += 256) {
            int kk = f >> 6, c = f & 63;
            Bs[kk * 68 + c] = Wq_[(size_t)(k0 + kk) * 256 + cb + c];
        }
        __syncthreads();
#pragma unroll
        for (int kk = 0; kk < 32; ++kk) {
            float4 a4 = *(const float4*)(As + kk * 68 + ty * 4);
            float4 b4 = *(const float4*)(Bs + kk * 68 + tx * 4);
            float av[4] = {a4.x, a4.y, a4.z, a4.w};
            float bv[4] = {b4.x, b4.y, b4.z, b4.w};
#pragma unroll
            for (int i = 0; i < 4; ++i)
#pragma unroll
                for (int j = 0; j < 4; ++j) acc[i][j] += av[i] * bv[j];
        }
    }
#pragma unroll
    for (int i = 0; i < 4; ++i)
#pragma unroll
        for (int j = 0; j < 4; ++j) {
            int n = rb + ty * 4 + i, k = cb + tx * 4 + j;
            int nt = n >> 4, kt = k >> 5, quad = (k & 31) >> 3, pos = k & 7;
            wqb_sw[((size_t)(nt * 8 + kt) * 64 + quad * 16 + (n & 15)) * 8 + pos] =
                (__hip_bfloat16)acc[i][j];
        }
}

// ---------------------------------------------------------------------------
// gi_gemm v2: all 4 t-steps staged at once -> ONE barrier (was 7) and a
// single burst of 96 MFMAs. xs[64][136] bf16 (17.4 KB): vrow = row*4 + tt.
// ---------------------------------------------------------------------------
__global__ __launch_bounds__(512) void gi_gemm(
    const float* __restrict__ node_input, const float* __restrict__ neighbors_input,
    const __hip_bfloat16* __restrict__ Wih_n_sw, const __hip_bfloat16* __restrict__ Wih_g_sw,
    const float* __restrict__ bih_node, const float* __restrict__ bhh_node,
    const float* __restrict__ bih_ngh,  const float* __restrict__ bhh_ngh,
    __hip_bfloat16* __restrict__ gi)
{
    __shared__ __align__(16) __hip_bfloat16 xs[64 * 136];
    const int tid = threadIdx.x, wave = tid >> 6, lane = tid & 63;
    const int quad = lane >> 4, lr = lane & 15;
    const int sblk = blockIdx.x >> 4, tc = blockIdx.x & 15;
    const bool isnode = (sblk < 4);
    const float* __restrict__ xb = isnode
        ? (node_input + (size_t)sblk * 16 * 64 * 128)
        : (neighbors_input + ((size_t)sblk * 16 - 64) * 64 * 128);
    const __hip_bfloat16* __restrict__ Wsw = isnode ? Wih_n_sw : Wih_g_sw;
    const float* __restrict__ bi = isnode ? bih_node : bih_ngh;
    const float* __restrict__ bh = isnode ? bhh_node : bhh_ngh;

    bf16x8 wfr[24];
#pragma unroll
    for (int nt = 0; nt < 6; ++nt)
#pragma unroll
        for (int kt = 0; kt < 4; ++kt)
            wfr[nt * 4 + kt] = *(const bf16x8*)(const void*)(
                Wsw + ((size_t)((wave * 6 + nt) * 4 + kt) * 64 + lane) * 8);

    float bias6[6];
#pragma unroll
    for (int tl = 0; tl < 6; ++tl) {
        int gate = tl >> 1;
        int col = gate * 256 + wave * 32 + (tl & 1) * 16 + lr;
        bias6[tl] = bi[col] + (gate < 2 ? bh[col] : 0.0f);
    }

    // stage 16 rows x 4 t-steps: vrow = r*4 + tt, 128 cols each
    {
        const int vr = tid >> 3, c0 = (tid & 7) * 16;
        const int r = vr >> 2, tt = vr & 3;
        const float* src = xb + ((size_t)r * 64 + tc * 4 + tt) * 128 + c0;
        float4 v0 = *(const float4*)(src);
        float4 v1 = *(const float4*)(src + 4);
        float4 v2 = *(const float4*)(src + 8);
        float4 v3 = *(const float4*)(src + 12);
        float vv[16] = {v0.x, v0.y, v0.z, v0.w, v1.x, v1.y, v1.z, v1.w,
                        v2.x, v2.y, v2.z, v2.w, v3.x, v3.y, v3.z, v3.w};
        __hip_bfloat16* d = xs + vr * 136 + c0;
#pragma unroll
        for (int j = 0; j < 16; ++j) d[j] = (__hip_bfloat16)vv[j];
    }
    __syncthreads();

    __hip_bfloat16* __restrict__ gout =
        gi + (size_t)((sblk * 8 + wave) * 6) * 16384 + (size_t)lane * 4;

#pragma unroll
    for (int tt = 0; tt < 4; ++tt) {
        int t = tc * 4 + tt;
        bf16x8 afr[4];
#pragma unroll
        for (int kt = 0; kt < 4; ++kt)
            afr[kt] = *(const bf16x8*)(const void*)(xs + (lr * 4 + tt) * 136 + kt * 32 + quad * 8);

#pragma unroll
        for (int tl = 0; tl < 6; ++tl) {
            f32x4 acc = {0.f, 0.f, 0.f, 0.f};
#pragma unroll
            for (int kt = 0; kt < 4; ++kt)
                acc = __builtin_amdgcn_mfma_f32_16x16x32_bf16(afr[kt], wfr[tl * 4 + kt], acc, 0, 0, 0);
            union { __hip_bfloat16 p[4]; uint2 u; } pu;
#pragma unroll
            for (int rg = 0; rg < 4; ++rg) pu.p[rg] = (__hip_bfloat16)(acc[rg] + bias6[tl]);
            *(uint2*)(void*)(gout + (size_t)tl * 16384 + (size_t)t * 256) = pu.u;
        }
    }
}

// ---------------------------------------------------------------------------
// scan_kernel (measured-best round-4/6 config — control, unchanged).
// ---------------------------------------------------------------------------
__global__ __launch_bounds__(512, 2) void scan_kernel(
    const __hip_bfloat16* __restrict__ gi,
    const __hip_bfloat16* __restrict__ Whh_n_sw,
    const __hip_bfloat16* __restrict__ Whh_g_sw,
    const float* __restrict__ bhh_node, const float* __restrict__ bhh_ngh,
    const float* __restrict__ node_hidden, const float* __restrict__ neighbors_hidden,
    __hip_bfloat16* __restrict__ node_out, __hip_bfloat16* __restrict__ ngh_out,
    float* __restrict__ out_node_hT, float* __restrict__ out_ngh_hT)
{
    __shared__ __align__(16) __hip_bfloat16 wlds[96 * 64 * 8];
    __shared__ __align__(16) __hip_bfloat16 hfr[2 * 4096];
    const int tid = threadIdx.x;
    const int wave = tid >> 6, lane = tid & 63;
    const int quad = lane >> 4, lr = lane & 15;
    const int row0 = blockIdx.x * 16;
    const bool isnode = (row0 < 64);
    const __hip_bfloat16* __restrict__ Wsw = isnode ? Whh_n_sw : Whh_g_sw;
    const float* __restrict__ bhh = isnode ? bhh_node : bhh_ngh;

    bf16x8 wreg[36];
#pragma unroll
    for (int nt = 0; nt < 6; ++nt)
#pragma unroll
        for (int kt = 0; kt < 6; ++kt)
            wreg[nt * 6 + kt] = *(const bf16x8*)(const void*)(
                Wsw + ((size_t)((wave * 6 + nt) * 8 + kt) * 64 + lane) * 8);

    for (int f = tid; f < 6144; f += 512) {
        int chunk = f >> 6, l = f & 63;
        int tileG = chunk >> 1, s = chunk & 1;
        *(uint4*)(void*)(wlds + ((size_t)chunk * 64 + l) * 8) =
            *(const uint4*)(const void*)(Wsw + ((size_t)(tileG * 8 + 6 + s) * 64 + l) * 8);
    }

    const __hip_bfloat16* __restrict__ gbase =
        gi + (size_t)((blockIdx.x * 8 + wave) * 6) * 16384 + (size_t)lane * 4;

    const float bhn0 = bhh[512 + wave * 32 + lr];
    const float bhn1 = bhh[512 + wave * 32 + 16 + lr];

    const int hwoff = (wave * 64 + (lr >> 3) * 16 + quad * 4) * 8 + (lr & 7);
    float hreg[8];
    {
        const float* hsrc = isnode ? (node_hidden + (size_t)row0 * 256)
                                   : (neighbors_hidden + (size_t)(row0 - 64) * 256);
#pragma unroll
        for (int half = 0; half < 2; ++half)
#pragma unroll
            for (int rg = 0; rg < 4; ++rg) {
                float v = hsrc[(size_t)(quad * 4 + rg) * 256 + wave * 32 + half * 16 + lr];
                hreg[half * 4 + rg] = v;
                hfr[hwoff + half * 256 + rg * 8] = (__hip_bfloat16)v;
            }
    }

    __hip_bfloat16* optr;
    {
        int orow = tid & 15;
        int ocol = (tid >> 6) * 32 + ((tid >> 4) & 3) * 8;
        optr = isnode ? (node_out + ((size_t)(row0 + orow) * 64) * 256 + ocol)
                      : (ngh_out + ((size_t)(row0 - 64 + orow) * 64) * 256 + ocol);
    }

    uint2 gv[6];
#pragma unroll
    for (int tl = 0; tl < 6; ++tl)
        gv[tl] = *(const uint2*)(const void*)(gbase + (size_t)tl * 16384);

    __syncthreads();

#pragma unroll 1
    for (int t = 0; t < 64; ++t) {
        const __hip_bfloat16* hr = hfr + (t & 1) * 4096;

        const int tp = (t < 63) ? (t + 1) : 63;
        uint2 gvn[6];
#pragma unroll
        for (int tl = 0; tl < 6; ++tl)
            gvn[tl] = *(const uint2*)(const void*)(gbase + (size_t)tl * 16384 + tp * 256);

        if (t) {
            uint4 ov = *(const uint4*)(const void*)(hr + tid * 8);
            *(uint4*)(void*)optr = ov;
            optr += 256;
        }

        f32x4 acc[6] = {{0.f,0.f,0.f,0.f},{0.f,0.f,0.f,0.f},{0.f,0.f,0.f,0.f},
                        {0.f,0.f,0.f,0.f},{0.f,0.f,0.f,0.f},{0.f,0.f,0.f,0.f}};
        {
#pragma unroll
            for (int kt = 0; kt < 3; ++kt) {
                bf16x8 av = *(const bf16x8*)(const void*)(hr + (kt * 64 + lane) * 8);
#pragma unroll
                for (int tl = 0; tl < 6; ++tl)
                    acc[tl] = __builtin_amdgcn_mfma_f32_16x16x32_bf16(av, wreg[tl * 6 + kt], acc[tl], 0, 0, 0);
            }
        }
        {
#pragma unroll
            for (int kt = 3; kt < 6; ++kt) {
                bf16x8 av = *(const bf16x8*)(const void*)(hr + (kt * 64 + lane) * 8);
#pragma unroll
                for (int tl = 0; tl < 6; ++tl)
                    acc[tl] = __builtin_amdgcn_mfma_f32_16x16x32_bf16(av, wreg[tl * 6 + kt], acc[tl], 0, 0, 0);
            }
        }
        {
#pragma unroll
            for (int s = 0; s < 2; ++s) {
                bf16x8 av = *(const bf16x8*)(const void*)(hr + ((6 + s) * 64 + lane) * 8);
#pragma unroll
                for (int tl = 0; tl < 6; ++tl) {
                    bf16x8 bfr = *(const bf16x8*)(const void*)(
                        wlds + ((size_t)((wave * 6 + tl) * 2 + s) * 64 + lane) * 8);
                    acc[tl] = __builtin_amdgcn_mfma_f32_16x16x32_bf16(av, bfr, acc[tl], 0, 0, 0);
                }
            }
        }

        __hip_bfloat16* hw = hfr + ((t + 1) & 1) * 4096 + hwoff;
#pragma unroll
        for (int half = 0; half < 2; ++half) {
            const float bhn = half ? bhn1 : bhn0;
#pragma unroll
            for (int rg = 0; rg < 4; ++rg) {
                float ghr = acc[half][rg];
                float ghz = acc[2 + half][rg];
                float ghn = acc[4 + half][rg] + bhn;
                float gir = bfsel(gv[half], rg);
                float giz = bfsel(gv[2 + half], rg);
                float gin = bfsel(gv[4 + half], rg);
                float r = sigmoidf_(gir + ghr);
                float z = sigmoidf_(giz + ghz);
                float n = tanhf_(gin + r * ghn);
                float hn = (1.0f - z) * n + z * hreg[half * 4 + rg];
                hreg[half * 4 + rg] = hn;
                hw[half * 256 + rg * 8] = (__hip_bfloat16)hn;
            }
        }
#pragma unroll
        for (int tl = 0; tl < 6; ++tl) gv[tl] = gvn[tl];

        asm volatile("s_waitcnt lgkmcnt(0)" ::: "memory");
        __builtin_amdgcn_s_barrier();
        __builtin_amdgcn_sched_barrier(0);
    }

    {
        uint4 ov = *(const uint4*)(const void*)(hfr + tid * 8);
        *(uint4*)(void*)optr = ov;
    }
    {
        float* hdst = isnode ? (out_node_hT + (size_t)row0 * 256)
                             : (out_ngh_hT + (size_t)(row0 - 64) * 256);
#pragma unroll
        for (int half = 0; half < 2; ++half)
#pragma unroll
            for (int rg = 0; rg < 4; ++rg)
                hdst[(size_t)(quad * 4 + rg) * 256 + wave * 32 + half * 16 + lr] = hreg[half * 4 + rg];
    }
}

// ---------------------------------------------------------------------------
// q_gemm: Qb = node_out @ wqb (node rows only).
// ---------------------------------------------------------------------------
__global__ __launch_bounds__(256) void q_gemm(
    const __hip_bfloat16* __restrict__ A0,
    const __hip_bfloat16* __restrict__ wqb_sw,
    __hip_bfloat16* __restrict__ Qb)
{
    __shared__ __align__(16) __hip_bfloat16 As[64 * 264];
    const int tid = threadIdx.x, wave = tid >> 6, lane = tid & 63;
    const int quad = lane >> 4, lr = lane & 15;
    const int rb = blockIdx.x * 64;
    const __hip_bfloat16* A = A0 + (size_t)rb * 256;

    for (int f = tid; f < 2048; f += 256) {
        int row = f >> 5, cc = (f & 31) * 8;
        *(uint4*)(void*)(As + row * 264 + cc) =
            *(const uint4*)(const void*)(A + (size_t)row * 256 + cc);
    }
    __syncthreads();

    bf16x8 afr[8];
#pragma unroll
    for (int kt = 0; kt < 8; ++kt)
        afr[kt] = *(const bf16x8*)(const void*)(As + (wave * 16 + lr) * 264 + kt * 32 + quad * 8);

    const int s0 = wave * 16 + quad * 4;
    for (int ntg = 0; ntg < 16; ++ntg) {
        f32x4 acc = {0.f, 0.f, 0.f, 0.f};
#pragma unroll
        for (int kt = 0; kt < 8; ++kt) {
            bf16x8 bfr = *(const bf16x8*)(const void*)(wqb_sw + ((size_t)(ntg * 8 + kt) * 64 + lane) * 8);
            acc = __builtin_amdgcn_mfma_f32_16x16x32_bf16(afr[kt], bfr, acc, 0, 0, 0);
        }
        int col = ntg * 16 + lr;
#pragma unroll
        for (int rg = 0; rg < 4; ++rg)
            Qb[(size_t)(rb + s0 + rg) * 256 + col] = (__hip_bfloat16)acc[rg];
    }
}

// ---------------------------------------------------------------------------
// attn_fused (validated round 9/11): per (b,m) block computes K and V tiles
// on the fly and consumes them from LDS — K/V never touch HBM.
// ---------------------------------------------------------------------------
__global__ __launch_bounds__(256) void attn_fused(
    const __hip_bfloat16* __restrict__ node_out_b,
    const __hip_bfloat16* __restrict__ ngh_out_b,
    const __hip_bfloat16* __restrict__ Wk_sw, const __hip_bfloat16* __restrict__ Wv_sw,
    const __hip_bfloat16* __restrict__ Qb, const float* __restrict__ bbil,
    const float* __restrict__ Wprj, const float* __restrict__ bprj,
    float* __restrict__ A_out, float* __restrict__ out)
{
    __shared__ __align__(16) __hip_bfloat16 KA[64 * 264];   // A -> K -> Vfrag
    __shared__ __align__(16) float Sbuf[64 * 68];
    __shared__ __align__(16) __hip_bfloat16 Pb[64 * 72];
    __shared__ float rowmax[64], rowrcp[64];
    __shared__ float red[64 * 16];
    const int tid = threadIdx.x;
    const int wave = tid >> 6, lane = tid & 63;
    const int quad = lane >> 4, lr = lane & 15;
    const int bm = blockIdx.x, b = bm / 17, m = bm % 17;
    const __hip_bfloat16* __restrict__ A = (m == 0)
        ? (node_out_b + (size_t)b * 64 * 256)
        : (ngh_out_b + ((size_t)(b * 16 + m - 1) * 64) * 256);

    // phase 0: stage A-tile
    for (int f = tid; f < 2048; f += 256) {
        int row = f >> 5, cc = (f & 31) * 8;
        *(uint4*)(void*)(KA + row * 264 + cc) =
            *(const uint4*)(const void*)(A + (size_t)row * 256 + cc);
    }
    __syncthreads();

    // phase 1: A-frags to regs; Q-frags from HBM (L2-hot, 17 readers/b)
    bf16x8 afr[8];
#pragma unroll
    for (int kt = 0; kt < 8; ++kt)
        afr[kt] = *(const bf16x8*)(const void*)(KA + (wave * 16 + lr) * 264 + kt * 32 + quad * 8);
    const __hip_bfloat16* Qrow = Qb + (size_t)b * 64 * 256;
    bf16x8 qfr[8];
#pragma unroll
    for (int kt = 0; kt < 8; ++kt)
        qfr[kt] = *(const bf16x8*)(const void*)(Qrow + (size_t)(wave * 16 + lr) * 256 + kt * 32 + quad * 8);
    __syncthreads();   // all afr reads done -> KA may be overwritten

    // phase 2: K = A @ Wk^T -> KA row-major (stride 264)
    {
        const int s0 = wave * 16 + quad * 4;
        for (int ntg = 0; ntg < 16; ++ntg) {
            f32x4 acc = {0.f, 0.f, 0.f, 0.f};
#pragma unroll
            for (int kt = 0; kt < 8; ++kt) {
                bf16x8 bfr = *(const bf16x8*)(const void*)(Wk_sw + ((size_t)(ntg * 8 + kt) * 64 + lane) * 8);
                acc = __builtin_amdgcn_mfma_f32_16x16x32_bf16(afr[kt], bfr, acc, 0, 0, 0);
            }
            int col = ntg * 16 + lr;
#pragma unroll
            for (int rg = 0; rg < 4; ++rg)
                KA[(s0 + rg) * 264 + col] = (__hip_bfloat16)acc[rg];
        }
    }
    __syncthreads();

    // phase 3: S = Q K^T (K read as B-frags from row-major LDS)
    f32x4 sacc[4] = {{0.f,0.f,0.f,0.f},{0.f,0.f,0.f,0.f},{0.f,0.f,0.f,0.f},{0.f,0.f,0.f,0.f}};
#pragma unroll
    for (int kt = 0; kt < 8; ++kt) {
#pragma unroll
        for (int c = 0; c < 4; ++c) {
            bf16x8 bfr = *(const bf16x8*)(const void*)(KA + (c * 16 + lr) * 264 + kt * 32 + quad * 8);
            sacc[c] = __builtin_amdgcn_mfma_f32_16x16x32_bf16(qfr[kt], bfr, sacc[c], 0, 0, 0);
        }
    }
#pragma unroll
    for (int c = 0; c < 4; ++c)
#pragma unroll
        for (int rg = 0; rg < 4; ++rg) {
            int t_ = wave * 16 + quad * 4 + rg, s_ = c * 16 + lr;
            Sbuf[t_ * 68 + s_] = (s_ <= t_) ? (sacc[c][rg] + bbil[s_]) : NEGV;
        }
    __syncthreads();   // QK reads of KA done -> KA may be overwritten by V

    // phase 4: V = A @ Wv^T -> KA as PV B-frags; softmax on tid<64
    {
        const int kt2 = wave >> 1;
        const int lp = ((wave & 1) * 2 + (quad >> 1)) * 16 + lr;
        const int j0 = (quad & 1) * 4;
        for (int ntg = 0; ntg < 16; ++ntg) {
            f32x4 acc = {0.f, 0.f, 0.f, 0.f};
#pragma unroll
            for (int kt = 0; kt < 8; ++kt) {
                bf16x8 bfr = *(const bf16x8*)(const void*)(Wv_sw + ((size_t)(ntg * 8 + kt) * 64 + lane) * 8);
                acc = __builtin_amdgcn_mfma_f32_16x16x32_bf16(afr[kt], bfr, acc, 0, 0, 0);
            }
            __hip_bfloat16 t4[4];
#pragma unroll
            for (int rg = 0; rg < 4; ++rg) t4[rg] = (__hip_bfloat16)acc[rg];
            *(uint2*)(void*)(KA + (size_t)(((ntg * 2 + kt2) * 64 + lp) * 8 + j0)) =
                *(const uint2*)(const void*)t4;
        }
    }
    if (tid < 64) {
        float mx = -3.0e38f;
        for (int s = 0; s < 64; ++s) mx = fmaxf(mx, Sbuf[tid * 68 + s]);
        float sum = 0.0f;
        for (int s = 0; s < 64; ++s) sum += __expf(Sbuf[tid * 68 + s] - mx);
        rowmax[tid] = mx;
        rowrcp[tid] = 1.0f / sum;
    }
    __syncthreads();

    // phase 5: P = softmax(S) -> A_out + Pb
    for (int idx = tid; idx < 4096; idx += 256) {
        int t_ = idx >> 6, s_ = idx & 63;
        float e = __expf(Sbuf[t_ * 68 + s_] - rowmax[t_]) * rowrcp[t_];
        A_out[(size_t)bm * 4096 + idx] = e;
        Pb[t_ * 72 + s_] = (__hip_bfloat16)e;
    }
    __syncthreads();

    // phase 6: ctx = P V, proj, reduce
    bf16x8 pfr[2];
#pragma unroll
    for (int k2 = 0; k2 < 2; ++k2)
        pfr[k2] = *(const bf16x8*)(const void*)(Pb + (wave * 16 + lr) * 72 + k2 * 32 + quad * 8);
    float part[4] = {0.f, 0.f, 0.f, 0.f};
#pragma unroll
    for (int nt = 0; nt < 16; ++nt) {
        f32x4 cacc = {0.f, 0.f, 0.f, 0.f};
#pragma unroll
        for (int k2 = 0; k2 < 2; ++k2) {
            bf16x8 bfr = *(const bf16x8*)(const void*)(KA + (size_t)((nt * 2 + k2) * 64 + lane) * 8);
            cacc = __builtin_amdgcn_mfma_f32_16x16x32_bf16(pfr[k2], bfr, cacc, 0, 0, 0);
        }
        float wp = Wprj[nt * 16 + lr];
#pragma unroll
        for (int rg = 0; rg < 4; ++rg) part[rg] += cacc[rg] * wp;
    }
#pragma unroll
    for (int rg = 0; rg < 4; ++rg) red[(wave * 16 + quad * 4 + rg) * 16 + lr] = part[rg];
    __syncthreads();
    if (tid < 64) {
        float s = 0.0f;
#pragma unroll
        for (int q = 0; q < 16; ++q) s += red[tid * 16 + q];
        if (m == 0) s += 17.0f * bprj[0];
        atomicAdd(out + b * 64 + tid, s);
    }
}

// ---------------------------------------------------------------------------
extern "C" void kernel_launch(void* const* d_in, const int* in_sizes, int n_in,
                              void* d_out, int out_size, void* d_ws, size_t ws_size,
                              hipStream_t stream)
{
    const float* node_input       = (const float*)d_in[0];
    const float* node_hidden      = (const float*)d_in[1];
    const float* neighbors_input  = (const float*)d_in[2];
    const float* neighbors_hidden = (const float*)d_in[3];
    const float* Wih_node = (const float*)d_in[5];
    const float* Whh_node = (const float*)d_in[6];
    const float* bih_node = (const float*)d_in[7];
    const float* bhh_node = (const float*)d_in[8];
    const float* Wih_ngh  = (const float*)d_in[9];
    const float* Whh_ngh  = (const float*)d_in[10];
    const float* bih_ngh  = (const float*)d_in[11];
    const float* bhh_ngh  = (const float*)d_in[12];
    const float* Wq   = (const float*)d_in[13];
    const float* Wk   = (const float*)d_in[14];
    const float* Wv   = (const float*)d_in[15];
    const float* Wbil = (const float*)d_in[16];
    const float* bbil = (const float*)d_in[17];
    const float* Wprj = (const float*)d_in[18];
    const float* bprj = (const float*)d_in[19];

    float* out         = (float*)d_out;          // (B,T)     4096
    float* out_node_hT = out + 4096;             // (1,B,H)   16384
    float* out_ngh_hT  = out + 20480;            // (1,B*N,H) 262144
    float* out_A       = out + 282624;           // (B,17,T,T)

    // ---- workspace layout (bytes) ----
    char* w = (char*)d_ws;
    __hip_bfloat16* Wih_n_sw = (__hip_bfloat16*)(w + 262144);    // 196608
    __hip_bfloat16* Wih_g_sw = (__hip_bfloat16*)(w + 458752);    // 196608
    __hip_bfloat16* Whh_n_sw = (__hip_bfloat16*)(w + 655360);    // 393216
    __hip_bfloat16* Whh_g_sw = (__hip_bfloat16*)(w + 1048576);   // 393216
    __hip_bfloat16* Wk_sw    = (__hip_bfloat16*)(w + 1441792);   // 131072
    __hip_bfloat16* Wv_sw    = (__hip_bfloat16*)(w + 1572864);   // 131072
    __hip_bfloat16* wqb_sw   = (__hip_bfloat16*)(w + 1703936);   // 131072
    __hip_bfloat16* node_out_b = (__hip_bfloat16*)(w + 1835008); // 2097152
    __hip_bfloat16* ngh_out_b  = (__hip_bfloat16*)(w + 3932160); // 33554432
    __hip_bfloat16* qb_b       = (__hip_bfloat16*)(w + 37486592);// 2097152
    __hip_bfloat16* gi         = (__hip_bfloat16*)(w + 39583744);// 106954752
    // end: 146538496 B

    hipMemsetAsync(d_out, 0, 4096 * sizeof(float), stream);

    convert_all<<<2832, 256, 0, stream>>>(
        Wih_node, Wih_ngh, Whh_node, Whh_ngh, Wk, Wv, Wbil, Wq,
        Wih_n_sw, Wih_g_sw, Whh_n_sw, Whh_g_sw, Wk_sw, Wv_sw, wqb_sw);

    gi_gemm<<<1088, 512, 0, stream>>>(
        node_input, neighbors_input, Wih_n_sw, Wih_g_sw,
        bih_node, bhh_node, bih_ngh, bhh_ngh, gi);

    scan_kernel<<<68, 512, 0, stream>>>(gi, Whh_n_sw, Whh_g_sw,
        bhh_node, bhh_ngh, node_hidden, neighbors_hidden,
        node_out_b, ngh_out_b, out_node_hT, out_ngh_hT);

    q_gemm<<<64, 256, 0, stream>>>(node_out_b, wqb_sw, qb_b);

    attn_fused<<<1088, 256, 0, stream>>>(
        node_out_b, ngh_out_b, Wk_sw, Wv_sw, qb_b, bbil, Wprj, bprj,
        out_A, out);
}

// Round 14
// 390.594 us; speedup vs baseline: 1.0577x; 1.0008x over previous
//
#include <hip/hip_runtime.h>
#include <hip/hip_bf16.h>

#define NEGV -1e30f
typedef __attribute__((ext_vector_type(8))) short bf16x8;
typedef __attribute__((ext_vector_type(4))) float f32x4;

__device__ __forceinline__ float rcpf_(float x) { return __builtin_amdgcn_rcpf(x); }
__device__ __forceinline__ float sigmoidf_(float x) { return rcpf_(1.0f + __expf(-x)); }
__device__ __forceinline__ float tanhf_(float x) {
    float ax = fabsf(x);
    float e = __expf(-2.0f * ax);
    float t = (1.0f - e) * rcpf_(1.0f + e);
    return copysignf(t, x);
}
__device__ __forceinline__ float bf2f(unsigned short u) {
    union { float f; unsigned int i; } x; x.i = ((unsigned int)u) << 16; return x.f;
}
__device__ __forceinline__ float bfsel(uint2 v, int rg) {
    unsigned int w = (rg < 2) ? v.x : v.y;
    return bf2f((unsigned short)((rg & 1) ? (w >> 16) : (w & 0xffffu)));
}

// ---------------------------------------------------------------------------
// bf16 MFMA-B swizzles.
// ---------------------------------------------------------------------------
__device__ __forceinline__ void swz_store(const float* __restrict__ src,
    __hip_bfloat16* __restrict__ dst, int idx, int kshift)
{
    int n = idx >> kshift, k = idx & ((1 << kshift) - 1);
    int nt = n >> 4, kt = k >> 5, quad = (k & 31) >> 3, pos = k & 7;
    dst[((size_t)((nt << (kshift - 5)) + kt) * 64 + quad * 16 + (n & 15)) * 8 + pos] =
        (__hip_bfloat16)src[idx];
}

__device__ __forceinline__ void swz_store_g(const float* __restrict__ src,
    __hip_bfloat16* __restrict__ dst, int idx, int kshift)
{
    int n = idx >> kshift, k = idx & ((1 << kshift) - 1);
    int gate = n >> 8, c = n & 255, w = c >> 5, half = (c >> 4) & 1;
    int tileG = w * 6 + gate * 2 + half;
    int kt = k >> 5, quad = (k & 31) >> 3, pos = k & 7;
    dst[((size_t)((tileG << (kshift - 5)) + kt) * 64 + quad * 16 + (n & 15)) * 8 + pos] =
        (__hip_bfloat16)src[idx];
}

// ---------------------------------------------------------------------------
// convert_all v2: swizzles + fused wqb GEMM tail (validated round 6).
// ---------------------------------------------------------------------------
__global__ __launch_bounds__(256) void convert_all(
    const float* __restrict__ Wih_n, const float* __restrict__ Wih_g,
    const float* __restrict__ Whh_n, const float* __restrict__ Whh_g,
    const float* __restrict__ Wk_,   const float* __restrict__ Wv_,
    const float* __restrict__ Wbil_, const float* __restrict__ Wq_,
    __hip_bfloat16* Wih_n_sw, __hip_bfloat16* Wih_g_sw,
    __hip_bfloat16* Whh_n_sw, __hip_bfloat16* Whh_g_sw,
    __hip_bfloat16* Wk_sw, __hip_bfloat16* Wv_sw, __hip_bfloat16* wqb_sw)
{
    __shared__ __align__(16) float As[32 * 68];
    __shared__ __align__(16) float Bs[32 * 68];
    if (blockIdx.x < 2816) {
        int g = blockIdx.x * 256 + threadIdx.x;   // < 720896
        if (g < 98304)        swz_store_g(Wih_n, Wih_n_sw, g, 7);
        else if (g < 196608)  swz_store_g(Wih_g, Wih_g_sw, g - 98304, 7);
        else if (g < 393216)  swz_store_g(Whh_n, Whh_n_sw, g - 196608, 8);
        else if (g < 589824)  swz_store_g(Whh_g, Whh_g_sw, g - 393216, 8);
        else if (g < 655360)  swz_store(Wk_,   Wk_sw,   g - 589824, 8);
        else                  swz_store(Wv_,   Wv_sw,   g - 655360, 8);
        return;
    }
    const int bx = blockIdx.x - 2816;
    const int tid = threadIdx.x, tx = tid & 15, ty = tid >> 4;
    const int rb = (bx >> 2) * 64, cb = (bx & 3) * 64;
    float acc[4][4] = {};
    for (int k0 = 0; k0 < 256; k0 += 32) {
        __syncthreads();
        for (int f = tid; f < 2048; f += 256) {
            int kk = f >> 6, r = f & 63;
            As[kk * 68 + r] = Wbil_[(size_t)(k0 + kk) * 256 + rb + r];
        }
        for (int f = tid; f < 2048; f += 256) {
            int kk = f >> 6, c = f & 63;
            Bs[kk * 68 + c] = Wq_[(size_t)(k0 + kk) * 256 + cb + c];
        }
        __syncthreads();
#pragma unroll
        for (int kk = 0; kk < 32; ++kk) {
            float4 a4 = *(const float4*)(As + kk * 68 + ty * 4);
            float4 b4 = *(const float4*)(Bs + kk * 68 + tx * 4);
            float av[4] = {a4.x, a4.y, a4.z, a4.w};
            float bv[4] = {b4.x, b4.y, b4.z, b4.w};
#pragma unroll
            for (int i = 0; i < 4; ++i)
#pragma unroll
                for (int j = 0; j < 4; ++j) acc[i][j] += av[i] * bv[j];
        }
    }
#pragma unroll
    for (int i = 0; i < 4; ++i)
#pragma unroll
        for (int j = 0; j < 4; ++j) {
            int n = rb + ty * 4 + i, k = cb + tx * 4 + j;
            int nt = n >> 4, kt = k >> 5, quad = (k & 31) >> 3, pos = k & 7;
            wqb_sw[((size_t)(nt * 8 + kt) * 64 + quad * 16 + (n & 15)) * 8 + pos] =
                (__hip_bfloat16)acc[i][j];
        }
}

// ---------------------------------------------------------------------------
// gi_gemm v2 (validated round 11/13 — unchanged).
// ---------------------------------------------------------------------------
__global__ __launch_bounds__(512) void gi_gemm(
    const float* __restrict__ node_input, const float* __restrict__ neighbors_input,
    const __hip_bfloat16* __restrict__ Wih_n_sw, const __hip_bfloat16* __restrict__ Wih_g_sw,
    const float* __restrict__ bih_node, const float* __restrict__ bhh_node,
    const float* __restrict__ bih_ngh,  const float* __restrict__ bhh_ngh,
    __hip_bfloat16* __restrict__ gi)
{
    __shared__ __align__(16) __hip_bfloat16 xs[64 * 136];
    const int tid = threadIdx.x, wave = tid >> 6, lane = tid & 63;
    const int quad = lane >> 4, lr = lane & 15;
    const int sblk = blockIdx.x >> 4, tc = blockIdx.x & 15;
    const bool isnode = (sblk < 4);
    const float* __restrict__ xb = isnode
        ? (node_input + (size_t)sblk * 16 * 64 * 128)
        : (neighbors_input + ((size_t)sblk * 16 - 64) * 64 * 128);
    const __hip_bfloat16* __restrict__ Wsw = isnode ? Wih_n_sw : Wih_g_sw;
    const float* __restrict__ bi = isnode ? bih_node : bih_ngh;
    const float* __restrict__ bh = isnode ? bhh_node : bhh_ngh;

    bf16x8 wfr[24];
#pragma unroll
    for (int nt = 0; nt < 6; ++nt)
#pragma unroll
        for (int kt = 0; kt < 4; ++kt)
            wfr[nt * 4 + kt] = *(const bf16x8*)(const void*)(
                Wsw + ((size_t)((wave * 6 + nt) * 4 + kt) * 64 + lane) * 8);

    float bias6[6];
#pragma unroll
    for (int tl = 0; tl < 6; ++tl) {
        int gate = tl >> 1;
        int col = gate * 256 + wave * 32 + (tl & 1) * 16 + lr;
        bias6[tl] = bi[col] + (gate < 2 ? bh[col] : 0.0f);
    }

    // stage 16 rows x 4 t-steps: vrow = r*4 + tt, 128 cols each
    {
        const int vr = tid >> 3, c0 = (tid & 7) * 16;
        const int r = vr >> 2, tt = vr & 3;
        const float* src = xb + ((size_t)r * 64 + tc * 4 + tt) * 128 + c0;
        float4 v0 = *(const float4*)(src);
        float4 v1 = *(const float4*)(src + 4);
        float4 v2 = *(const float4*)(src + 8);
        float4 v3 = *(const float4*)(src + 12);
        float vv[16] = {v0.x, v0.y, v0.z, v0.w, v1.x, v1.y, v1.z, v1.w,
                        v2.x, v2.y, v2.z, v2.w, v3.x, v3.y, v3.z, v3.w};
        __hip_bfloat16* d = xs + vr * 136 + c0;
#pragma unroll
        for (int j = 0; j < 16; ++j) d[j] = (__hip_bfloat16)vv[j];
    }
    __syncthreads();

    __hip_bfloat16* __restrict__ gout =
        gi + (size_t)((sblk * 8 + wave) * 6) * 16384 + (size_t)lane * 4;

#pragma unroll
    for (int tt = 0; tt < 4; ++tt) {
        int t = tc * 4 + tt;
        bf16x8 afr[4];
#pragma unroll
        for (int kt = 0; kt < 4; ++kt)
            afr[kt] = *(const bf16x8*)(const void*)(xs + (lr * 4 + tt) * 136 + kt * 32 + quad * 8);

#pragma unroll
        for (int tl = 0; tl < 6; ++tl) {
            f32x4 acc = {0.f, 0.f, 0.f, 0.f};
#pragma unroll
            for (int kt = 0; kt < 4; ++kt)
                acc = __builtin_amdgcn_mfma_f32_16x16x32_bf16(afr[kt], wfr[tl * 4 + kt], acc, 0, 0, 0);
            union { __hip_bfloat16 p[4]; uint2 u; } pu;
#pragma unroll
            for (int rg = 0; rg < 4; ++rg) pu.p[rg] = (__hip_bfloat16)(acc[rg] + bias6[tl]);
            *(uint2*)(void*)(gout + (size_t)tl * 16384 + (size_t)t * 256) = pu.u;
        }
    }
}

// ---------------------------------------------------------------------------
// scan_kernel (measured-best round-4/6 config — control, unchanged).
// ---------------------------------------------------------------------------
__global__ __launch_bounds__(512, 2) void scan_kernel(
    const __hip_bfloat16* __restrict__ gi,
    const __hip_bfloat16* __restrict__ Whh_n_sw,
    const __hip_bfloat16* __restrict__ Whh_g_sw,
    const float* __restrict__ bhh_node, const float* __restrict__ bhh_ngh,
    const float* __restrict__ node_hidden, const float* __restrict__ neighbors_hidden,
    __hip_bfloat16* __restrict__ node_out, __hip_bfloat16* __restrict__ ngh_out,
    float* __restrict__ out_node_hT, float* __restrict__ out_ngh_hT)
{
    __shared__ __align__(16) __hip_bfloat16 wlds[96 * 64 * 8];
    __shared__ __align__(16) __hip_bfloat16 hfr[2 * 4096];
    const int tid = threadIdx.x;
    const int wave = tid >> 6, lane = tid & 63;
    const int quad = lane >> 4, lr = lane & 15;
    const int row0 = blockIdx.x * 16;
    const bool isnode = (row0 < 64);
    const __hip_bfloat16* __restrict__ Wsw = isnode ? Whh_n_sw : Whh_g_sw;
    const float* __restrict__ bhh = isnode ? bhh_node : bhh_ngh;

    bf16x8 wreg[36];
#pragma unroll
    for (int nt = 0; nt < 6; ++nt)
#pragma unroll
        for (int kt = 0; kt < 6; ++kt)
            wreg[nt * 6 + kt] = *(const bf16x8*)(const void*)(
                Wsw + ((size_t)((wave * 6 + nt) * 8 + kt) * 64 + lane) * 8);

    for (int f = tid; f < 6144; f += 512) {
        int chunk = f >> 6, l = f & 63;
        int tileG = chunk >> 1, s = chunk & 1;
        *(uint4*)(void*)(wlds + ((size_t)chunk * 64 + l) * 8) =
            *(const uint4*)(const void*)(Wsw + ((size_t)(tileG * 8 + 6 + s) * 64 + l) * 8);
    }

    const __hip_bfloat16* __restrict__ gbase =
        gi + (size_t)((blockIdx.x * 8 + wave) * 6) * 16384 + (size_t)lane * 4;

    const float bhn0 = bhh[512 + wave * 32 + lr];
    const float bhn1 = bhh[512 + wave * 32 + 16 + lr];

    const int hwoff = (wave * 64 + (lr >> 3) * 16 + quad * 4) * 8 + (lr & 7);
    float hreg[8];
    {
        const float* hsrc = isnode ? (node_hidden + (size_t)row0 * 256)
                                   : (neighbors_hidden + (size_t)(row0 - 64) * 256);
#pragma unroll
        for (int half = 0; half < 2; ++half)
#pragma unroll
            for (int rg = 0; rg < 4; ++rg) {
                float v = hsrc[(size_t)(quad * 4 + rg) * 256 + wave * 32 + half * 16 + lr];
                hreg[half * 4 + rg] = v;
                hfr[hwoff + half * 256 + rg * 8] = (__hip_bfloat16)v;
            }
    }

    __hip_bfloat16* optr;
    {
        int orow = tid & 15;
        int ocol = (tid >> 6) * 32 + ((tid >> 4) & 3) * 8;
        optr = isnode ? (node_out + ((size_t)(row0 + orow) * 64) * 256 + ocol)
                      : (ngh_out + ((size_t)(row0 - 64 + orow) * 64) * 256 + ocol);
    }

    uint2 gv[6];
#pragma unroll
    for (int tl = 0; tl < 6; ++tl)
        gv[tl] = *(const uint2*)(const void*)(gbase + (size_t)tl * 16384);

    __syncthreads();

#pragma unroll 1
    for (int t = 0; t < 64; ++t) {
        const __hip_bfloat16* hr = hfr + (t & 1) * 4096;

        const int tp = (t < 63) ? (t + 1) : 63;
        uint2 gvn[6];
#pragma unroll
        for (int tl = 0; tl < 6; ++tl)
            gvn[tl] = *(const uint2*)(const void*)(gbase + (size_t)tl * 16384 + tp * 256);

        if (t) {
            uint4 ov = *(const uint4*)(const void*)(hr + tid * 8);
            *(uint4*)(void*)optr = ov;
            optr += 256;
        }

        f32x4 acc[6] = {{0.f,0.f,0.f,0.f},{0.f,0.f,0.f,0.f},{0.f,0.f,0.f,0.f},
                        {0.f,0.f,0.f,0.f},{0.f,0.f,0.f,0.f},{0.f,0.f,0.f,0.f}};
        {
#pragma unroll
            for (int kt = 0; kt < 3; ++kt) {
                bf16x8 av = *(const bf16x8*)(const void*)(hr + (kt * 64 + lane) * 8);
#pragma unroll
                for (int tl = 0; tl < 6; ++tl)
                    acc[tl] = __builtin_amdgcn_mfma_f32_16x16x32_bf16(av, wreg[tl * 6 + kt], acc[tl], 0, 0, 0);
            }
        }
        {
#pragma unroll
            for (int kt = 3; kt < 6; ++kt) {
                bf16x8 av = *(const bf16x8*)(const void*)(hr + (kt * 64 + lane) * 8);
#pragma unroll
                for (int tl = 0; tl < 6; ++tl)
                    acc[tl] = __builtin_amdgcn_mfma_f32_16x16x32_bf16(av, wreg[tl * 6 + kt], acc[tl], 0, 0, 0);
            }
        }
        {
#pragma unroll
            for (int s = 0; s < 2; ++s) {
                bf16x8 av = *(const bf16x8*)(const void*)(hr + ((6 + s) * 64 + lane) * 8);
#pragma unroll
                for (int tl = 0; tl < 6; ++tl) {
                    bf16x8 bfr = *(const bf16x8*)(const void*)(
                        wlds + ((size_t)((wave * 6 + tl) * 2 + s) * 64 + lane) * 8);
                    acc[tl] = __builtin_amdgcn_mfma_f32_16x16x32_bf16(av, bfr, acc[tl], 0, 0, 0);
                }
            }
        }

        __hip_bfloat16* hw = hfr + ((t + 1) & 1) * 4096 + hwoff;
#pragma unroll
        for (int half = 0; half < 2; ++half) {
            const float bhn = half ? bhn1 : bhn0;
#pragma unroll
            for (int rg = 0; rg < 4; ++rg) {
                float ghr = acc[half][rg];
                float ghz = acc[2 + half][rg];
                float ghn = acc[4 + half][rg] + bhn;
                float gir = bfsel(gv[half], rg);
                float giz = bfsel(gv[2 + half], rg);
                float gin = bfsel(gv[4 + half], rg);
                float r = sigmoidf_(gir + ghr);
                float z = sigmoidf_(giz + ghz);
                float n = tanhf_(gin + r * ghn);
                float hn = (1.0f - z) * n + z * hreg[half * 4 + rg];
                hreg[half * 4 + rg] = hn;
                hw[half * 256 + rg * 8] = (__hip_bfloat16)hn;
            }
        }
#pragma unroll
        for (int tl = 0; tl < 6; ++tl) gv[tl] = gvn[tl];

        asm volatile("s_waitcnt lgkmcnt(0)" ::: "memory");
        __builtin_amdgcn_s_barrier();
        __builtin_amdgcn_sched_barrier(0);
    }

    {
        uint4 ov = *(const uint4*)(const void*)(hfr + tid * 8);
        *(uint4*)(void*)optr = ov;
    }
    {
        float* hdst = isnode ? (out_node_hT + (size_t)row0 * 256)
                             : (out_ngh_hT + (size_t)(row0 - 64) * 256);
#pragma unroll
        for (int half = 0; half < 2; ++half)
#pragma unroll
            for (int rg = 0; rg < 4; ++rg)
                hdst[(size_t)(quad * 4 + rg) * 256 + wave * 32 + half * 16 + lr] = hreg[half * 4 + rg];
    }
}

// ---------------------------------------------------------------------------
// q_gemm: Qb = node_out @ wqb (node rows only) — unchanged.
// ---------------------------------------------------------------------------
__global__ __launch_bounds__(256) void q_gemm(
    const __hip_bfloat16* __restrict__ A0,
    const __hip_bfloat16* __restrict__ wqb_sw,
    __hip_bfloat16* __restrict__ Qb)
{
    __shared__ __align__(16) __hip_bfloat16 As[64 * 264];
    const int tid = threadIdx.x, wave = tid >> 6, lane = tid & 63;
    const int quad = lane >> 4, lr = lane & 15;
    const int rb = blockIdx.x * 64;
    const __hip_bfloat16* A = A0 + (size_t)rb * 256;

    for (int f = tid; f < 2048; f += 256) {
        int row = f >> 5, cc = (f & 31) * 8;
        *(uint4*)(void*)(As + row * 264 + cc) =
            *(const uint4*)(const void*)(A + (size_t)row * 256 + cc);
    }
    __syncthreads();

    bf16x8 afr[8];
#pragma unroll
    for (int kt = 0; kt < 8; ++kt)
        afr[kt] = *(const bf16x8*)(const void*)(As + (wave * 16 + lr) * 264 + kt * 32 + quad * 8);

    const int s0 = wave * 16 + quad * 4;
    for (int ntg = 0; ntg < 16; ++ntg) {
        f32x4 acc = {0.f, 0.f, 0.f, 0.f};
#pragma unroll
        for (int kt = 0; kt < 8; ++kt) {
            bf16x8 bfr = *(const bf16x8*)(const void*)(wqb_sw + ((size_t)(ntg * 8 + kt) * 64 + lane) * 8);
            acc = __builtin_amdgcn_mfma_f32_16x16x32_bf16(afr[kt], bfr, acc, 0, 0, 0);
        }
        int col = ntg * 16 + lr;
#pragma unroll
        for (int rg = 0; rg < 4; ++rg)
            Qb[(size_t)(rb + s0 + rg) * 256 + col] = (__hip_bfloat16)acc[rg];
    }
}

// ---------------------------------------------------------------------------
// attn_fused v3: identical to the validated round-9/13 kernel except the
// row-softmax reduce is parallelized across ALL 256 threads (4 threads/row,
// 16 cols each, 2-step __shfl_xor inside the 4-lane group) — removes the
// tid<64 serial 2x64-iteration tail that left waves 1-3 idle at the barrier.
// ---------------------------------------------------------------------------
__global__ __launch_bounds__(256) void attn_fused(
    const __hip_bfloat16* __restrict__ node_out_b,
    const __hip_bfloat16* __restrict__ ngh_out_b,
    const __hip_bfloat16* __restrict__ Wk_sw, const __hip_bfloat16* __restrict__ Wv_sw,
    const __hip_bfloat16* __restrict__ Qb, const float* __restrict__ bbil,
    const float* __restrict__ Wprj, const float* __restrict__ bprj,
    float* __restrict__ A_out, float* __restrict__ out)
{
    __shared__ __align__(16) __hip_bfloat16 KA[64 * 264];   // A -> K -> Vfrag
    __shared__ __align__(16) float Sbuf[64 * 68];
    __shared__ __align__(16) __hip_bfloat16 Pb[64 * 72];
    __shared__ float rowmax[64], rowrcp[64];
    __shared__ float red[64 * 16];
    const int tid = threadIdx.x;
    const int wave = tid >> 6, lane = tid & 63;
    const int quad = lane >> 4, lr = lane & 15;
    const int bm = blockIdx.x, b = bm / 17, m = bm % 17;
    const __hip_bfloat16* __restrict__ A = (m == 0)
        ? (node_out_b + (size_t)b * 64 * 256)
        : (ngh_out_b + ((size_t)(b * 16 + m - 1) * 64) * 256);

    // phase 0: stage A-tile
    for (int f = tid; f < 2048; f += 256) {
        int row = f >> 5, cc = (f & 31) * 8;
        *(uint4*)(void*)(KA + row * 264 + cc) =
            *(const uint4*)(const void*)(A + (size_t)row * 256 + cc);
    }
    __syncthreads();

    // phase 1: A-frags to regs; Q-frags from HBM (L2-hot, 17 readers/b)
    bf16x8 afr[8];
#pragma unroll
    for (int kt = 0; kt < 8; ++kt)
        afr[kt] = *(const bf16x8*)(const void*)(KA + (wave * 16 + lr) * 264 + kt * 32 + quad * 8);
    const __hip_bfloat16* Qrow = Qb + (size_t)b * 64 * 256;
    bf16x8 qfr[8];
#pragma unroll
    for (int kt = 0; kt < 8; ++kt)
        qfr[kt] = *(const bf16x8*)(const void*)(Qrow + (size_t)(wave * 16 + lr) * 256 + kt * 32 + quad * 8);
    __syncthreads();   // all afr reads done -> KA may be overwritten

    // phase 2: K = A @ Wk^T -> KA row-major (stride 264)
    {
        const int s0 = wave * 16 + quad * 4;
        for (int ntg = 0; ntg < 16; ++ntg) {
            f32x4 acc = {0.f, 0.f, 0.f, 0.f};
#pragma unroll
            for (int kt = 0; kt < 8; ++kt) {
                bf16x8 bfr = *(const bf16x8*)(const void*)(Wk_sw + ((size_t)(ntg * 8 + kt) * 64 + lane) * 8);
                acc = __builtin_amdgcn_mfma_f32_16x16x32_bf16(afr[kt], bfr, acc, 0, 0, 0);
            }
            int col = ntg * 16 + lr;
#pragma unroll
            for (int rg = 0; rg < 4; ++rg)
                KA[(s0 + rg) * 264 + col] = (__hip_bfloat16)acc[rg];
        }
    }
    __syncthreads();

    // phase 3: S = Q K^T (K read as B-frags from row-major LDS)
    f32x4 sacc[4] = {{0.f,0.f,0.f,0.f},{0.f,0.f,0.f,0.f},{0.f,0.f,0.f,0.f},{0.f,0.f,0.f,0.f}};
#pragma unroll
    for (int kt = 0; kt < 8; ++kt) {
#pragma unroll
        for (int c = 0; c < 4; ++c) {
            bf16x8 bfr = *(const bf16x8*)(const void*)(KA + (c * 16 + lr) * 264 + kt * 32 + quad * 8);
            sacc[c] = __builtin_amdgcn_mfma_f32_16x16x32_bf16(qfr[kt], bfr, sacc[c], 0, 0, 0);
        }
    }
#pragma unroll
    for (int c = 0; c < 4; ++c)
#pragma unroll
        for (int rg = 0; rg < 4; ++rg) {
            int t_ = wave * 16 + quad * 4 + rg, s_ = c * 16 + lr;
            Sbuf[t_ * 68 + s_] = (s_ <= t_) ? (sacc[c][rg] + bbil[s_]) : NEGV;
        }
    __syncthreads();   // QK reads of KA done -> KA may be overwritten by V

    // phase 4: V = A @ Wv^T -> KA as PV B-frags; then ALL-thread softmax reduce
    {
        const int kt2 = wave >> 1;
        const int lp = ((wave & 1) * 2 + (quad >> 1)) * 16 + lr;
        const int j0 = (quad & 1) * 4;
        for (int ntg = 0; ntg < 16; ++ntg) {
            f32x4 acc = {0.f, 0.f, 0.f, 0.f};
#pragma unroll
            for (int kt = 0; kt < 8; ++kt) {
                bf16x8 bfr = *(const bf16x8*)(const void*)(Wv_sw + ((size_t)(ntg * 8 + kt) * 64 + lane) * 8);
                acc = __builtin_amdgcn_mfma_f32_16x16x32_bf16(afr[kt], bfr, acc, 0, 0, 0);
            }
            __hip_bfloat16 t4[4];
#pragma unroll
            for (int rg = 0; rg < 4; ++rg) t4[rg] = (__hip_bfloat16)acc[rg];
            *(uint2*)(void*)(KA + (size_t)(((ntg * 2 + kt2) * 64 + lp) * 8 + j0)) =
                *(const uint2*)(const void*)t4;
        }
    }
    {
        const int row = tid >> 2, seg = (tid & 3) * 16;
        float mx = -3.0e38f;
#pragma unroll
        for (int s = 0; s < 16; ++s) mx = fmaxf(mx, Sbuf[row * 68 + seg + s]);
        mx = fmaxf(mx, __shfl_xor(mx, 1));
        mx = fmaxf(mx, __shfl_xor(mx, 2));
        float sum = 0.0f;
#pragma unroll
        for (int s = 0; s < 16; ++s) sum += __expf(Sbuf[row * 68 + seg + s] - mx);
        sum += __shfl_xor(sum, 1);
        sum += __shfl_xor(sum, 2);
        if ((tid & 3) == 0) { rowmax[row] = mx; rowrcp[row] = 1.0f / sum; }
    }
    __syncthreads();

    // phase 5: P = softmax(S) -> A_out + Pb
    for (int idx = tid; idx < 4096; idx += 256) {
        int t_ = idx >> 6, s_ = idx & 63;
        float e = __expf(Sbuf[t_ * 68 + s_] - rowmax[t_]) * rowrcp[t_];
        A_out[(size_t)bm * 4096 + idx] = e;
        Pb[t_ * 72 + s_] = (__hip_bfloat16)e;
    }
    __syncthreads();

    // phase 6: ctx = P V, proj, reduce
    bf16x8 pfr[2];
#pragma unroll
    for (int k2 = 0; k2 < 2; ++k2)
        pfr[k2] = *(const bf16x8*)(const void*)(Pb + (wave * 16 + lr) * 72 + k2 * 32 + quad * 8);
    float part[4] = {0.f, 0.f, 0.f, 0.f};
#pragma unroll
    for (int nt = 0; nt < 16; ++nt) {
        f32x4 cacc = {0.f, 0.f, 0.f, 0.f};
#pragma unroll
        for (int k2 = 0; k2 < 2; ++k2) {
            bf16x8 bfr = *(const bf16x8*)(const void*)(KA + (size_t)((nt * 2 + k2) * 64 + lane) * 8);
            cacc = __builtin_amdgcn_mfma_f32_16x16x32_bf16(pfr[k2], bfr, cacc, 0, 0, 0);
        }
        float wp = Wprj[nt * 16 + lr];
#pragma unroll
        for (int rg = 0; rg < 4; ++rg) part[rg] += cacc[rg] * wp;
    }
#pragma unroll
    for (int rg = 0; rg < 4; ++rg) red[(wave * 16 + quad * 4 + rg) * 16 + lr] = part[rg];
    __syncthreads();
    if (tid < 64) {
        float s = 0.0f;
#pragma unroll
        for (int q = 0; q < 16; ++q) s += red[tid * 16 + q];
        if (m == 0) s += 17.0f * bprj[0];
        atomicAdd(out + b * 64 + tid, s);
    }
}

// ---------------------------------------------------------------------------
extern "C" void kernel_launch(void* const* d_in, const int* in_sizes, int n_in,
                              void* d_out, int out_size, void* d_ws, size_t ws_size,
                              hipStream_t stream)
{
    const float* node_input       = (const float*)d_in[0];
    const float* node_hidden      = (const float*)d_in[1];
    const float* neighbors_input  = (const float*)d_in[2];
    const float* neighbors_hidden = (const float*)d_in[3];
    const float* Wih_node = (const float*)d_in[5];
    const float* Whh_node = (const float*)d_in[6];
    const float* bih_node = (const float*)d_in[7];
    const float* bhh_node = (const float*)d_in[8];
    const float* Wih_ngh  = (const float*)d_in[9];
    const float* Whh_ngh  = (const float*)d_in[10];
    const float* bih_ngh  = (const float*)d_in[11];
    const float* bhh_ngh  = (const float*)d_in[12];
    const float* Wq   = (const float*)d_in[13];
    const float* Wk   = (const float*)d_in[14];
    const float* Wv   = (const float*)d_in[15];
    const float* Wbil = (const float*)d_in[16];
    const float* bbil = (const float*)d_in[17];
    const float* Wprj = (const float*)d_in[18];
    const float* bprj = (const float*)d_in[19];

    float* out         = (float*)d_out;          // (B,T)     4096
    float* out_node_hT = out + 4096;             // (1,B,H)   16384
    float* out_ngh_hT  = out + 20480;            // (1,B*N,H) 262144
    float* out_A       = out + 282624;           // (B,17,T,T)

    // ---- workspace layout (bytes) ----
    char* w = (char*)d_ws;
    __hip_bfloat16* Wih_n_sw = (__hip_bfloat16*)(w + 262144);    // 196608
    __hip_bfloat16* Wih_g_sw = (__hip_bfloat16*)(w + 458752);    // 196608
    __hip_bfloat16* Whh_n_sw = (__hip_bfloat16*)(w + 655360);    // 393216
    __hip_bfloat16* Whh_g_sw = (__hip_bfloat16*)(w + 1048576);   // 393216
    __hip_bfloat16* Wk_sw    = (__hip_bfloat16*)(w + 1441792);   // 131072
    __hip_bfloat16* Wv_sw    = (__hip_bfloat16*)(w + 1572864);   // 131072
    __hip_bfloat16* wqb_sw   = (__hip_bfloat16*)(w + 1703936);   // 131072
    __hip_bfloat16* node_out_b = (__hip_bfloat16*)(w + 1835008); // 2097152
    __hip_bfloat16* ngh_out_b  = (__hip_bfloat16*)(w + 3932160); // 33554432
    __hip_bfloat16* qb_b       = (__hip_bfloat16*)(w + 37486592);// 2097152
    __hip_bfloat16* gi         = (__hip_bfloat16*)(w + 39583744);// 106954752
    // end: 146538496 B

    hipMemsetAsync(d_out, 0, 4096 * sizeof(float), stream);

    convert_all<<<2832, 256, 0, stream>>>(
        Wih_node, Wih_ngh, Whh_node, Whh_ngh, Wk, Wv, Wbil, Wq,
        Wih_n_sw, Wih_g_sw, Whh_n_sw, Whh_g_sw, Wk_sw, Wv_sw, wqb_sw);

    gi_gemm<<<1088, 512, 0, stream>>>(
        node_input, neighbors_input, Wih_n_sw, Wih_g_sw,
        bih_node, bhh_node, bih_ngh, bhh_ngh, gi);

    scan_kernel<<<68, 512, 0, stream>>>(gi, Whh_n_sw, Whh_g_sw,
        bhh_node, bhh_ngh, node_hidden, neighbors_hidden,
        node_out_b, ngh_out_b, out_node_hT, out_ngh_hT);

    q_gemm<<<64, 256, 0, stream>>>(node_out_b, wqb_sw, qb_b);

    attn_fused<<<1088, 256, 0, stream>>>(
        node_out_b, ngh_out_b, Wk_sw, Wv_sw, qb_b, bbil, Wprj, bprj,
        out_A, out);
}